// Round 6
// baseline (397.183 us; speedup 1.0000x reference)
//
#include <hip/hip_runtime.h>

// MHA: B=4, S=2048, D=1024, H=16, Dh=64.  M = B*S = 8192.
// bf16 MFMA 16x16x32 (verified layouts):
//   C/D: col = lane&15, row = (lane>>4)*4 + reg
//   A  : A[m = lane&15][k = (lane>>4)*8 + j]
//   B  : B[k = (lane>>4)*8 + j][n = lane&15]
// R5 finding: global_load_lds staging runs at ~10.8 B/cyc/CU regardless of L2
// hits -> all MFMA kernels were staged-traffic-bound. R6: bigger tiles (halve
// bytes/FLOP), hybrid staging (A via DMA path, W via regular-load path),
// flash BQ=256 (halve K/V rereads).

typedef short bf16x8 __attribute__((ext_vector_type(8)));
typedef short bf16x4 __attribute__((ext_vector_type(4)));
typedef float f32x4 __attribute__((ext_vector_type(4)));

__device__ __forceinline__ short f2bf(float x) {  // RNE
    union { float f; unsigned int u; } un; un.f = x;
    unsigned int u = un.u;
    return (short)(unsigned short)((u + 0x7fffu + ((u >> 16) & 1u)) >> 16);
}

__device__ __forceinline__ void gll16(const void* g, void* l) {
    __builtin_amdgcn_global_load_lds(
        (const __attribute__((address_space(1))) void*)g,
        (__attribute__((address_space(3))) void*)l, 16, 0, 0);
}

// ---- fused fp32 -> bf16 convert ----
struct CvtArgs { const float* s[4]; unsigned short* d[4]; int n4; };
__global__ __launch_bounds__(256) void cvt_bf16(CvtArgs ca) {
    const float* s = ca.s[blockIdx.y];
    unsigned short* d = ca.d[blockIdx.y];
    int i = blockIdx.x * blockDim.x + threadIdx.x;
    int stride = gridDim.x * blockDim.x;
    const float4* s4 = reinterpret_cast<const float4*>(s);
    bf16x4* d4 = reinterpret_cast<bf16x4*>(d);
    for (; i < ca.n4; i += stride) {
        float4 x = s4[i];
        bf16x4 y;
        y[0] = f2bf(x.x); y[1] = f2bf(x.y); y[2] = f2bf(x.z); y[3] = f2bf(x.w);
        d4[i] = y;
    }
}

// ---- GEMM core: C[8192][1024] = A @ W^T, val = (acc+bias)*scale ----
// TM x TN tile, BK=32 ping-pong. Wave-tile 64x128 (acc[4][8]).
// A staged via global_load_lds (DMA path); W staged via regular loads
// (VGPR/L2 path). XOR-chunk swizzle (chunk ^= row&3) on both.
// mode 0: fp32 [M][N] ; mode 1: bf16 [b*16+h][s][d] ; mode 2: bf16 [b*16+h][d][s]
template <int TM, int TN>
__device__ __forceinline__ void gemm_core(const unsigned short* __restrict__ A,
                                          const unsigned short* __restrict__ W,
                                          const float* __restrict__ bias,
                                          float scale, void* __restrict__ out,
                                          int mode) {
    constexpr int NWM = TM / 64, NWN = TN / 128;
    constexpr int NT = NWM * NWN * 64;
    constexpr int CA = TM * 4;  // 16B chunks per k-slab
    constexpr int CB = TN * 4;
    __shared__ unsigned short As[2][TM * 32];
    __shared__ unsigned short Bs[2][TN * 32];
    const int tid = threadIdx.x;
    const int m0 = blockIdx.y * TM, n0 = blockIdx.x * TN;
    const int wave = tid >> 6, lane = tid & 63;
    const int wm = (wave % NWM) * 64, wn = (wave / NWM) * 128;
    const int l15 = lane & 15, quad = lane >> 4;

    f32x4 acc[4][8] = {};

#define STAGE_A(K0, PB)                                                           \
    {                                                                             \
        _Pragma("unroll") for (int c0 = 0; c0 < CA; c0 += NT) {                   \
            int c = c0 + tid;                                                     \
            int row = c >> 2, ch = (c & 3) ^ (row & 3);                           \
            gll16(&A[(size_t)(m0 + row) * 1024 + (K0) + ch * 8], &As[PB][c * 8]); \
        }                                                                         \
    }
#define STAGE_B(K0, PB)                                                           \
    {                                                                             \
        _Pragma("unroll") for (int c0 = 0; c0 < CB; c0 += NT) {                   \
            int c = c0 + tid;                                                     \
            int row = c >> 2, ch = (c & 3) ^ (row & 3);                           \
            *reinterpret_cast<bf16x8*>(&Bs[PB][c * 8]) =                          \
                *reinterpret_cast<const bf16x8*>(                                 \
                    &W[(size_t)(n0 + row) * 1024 + (K0) + ch * 8]);               \
        }                                                                         \
    }

    STAGE_A(0, 0);
    STAGE_B(0, 0);
    __syncthreads();

    for (int it = 0; it < 32; ++it) {
        const int pb = it & 1;
        if (it < 31) {
            STAGE_A((it + 1) * 32, pb ^ 1);
            STAGE_B((it + 1) * 32, pb ^ 1);
        }
        bf16x8 a[4], b[8];
#pragma unroll
        for (int i = 0; i < 4; ++i) {
            int row = wm + i * 16 + l15;
            a[i] = *reinterpret_cast<bf16x8*>(&As[pb][row * 32 + (quad ^ (row & 3)) * 8]);
        }
#pragma unroll
        for (int j = 0; j < 8; ++j) {
            int row = wn + j * 16 + l15;
            b[j] = *reinterpret_cast<bf16x8*>(&Bs[pb][row * 32 + (quad ^ (row & 3)) * 8]);
        }
#pragma unroll
        for (int i = 0; i < 4; ++i)
#pragma unroll
            for (int j = 0; j < 8; ++j)
                acc[i][j] = __builtin_amdgcn_mfma_f32_16x16x32_bf16(a[i], b[j], acc[i][j], 0, 0, 0);
        __syncthreads();
    }
#undef STAGE_A
#undef STAGE_B

#pragma unroll
    for (int i = 0; i < 4; ++i) {
#pragma unroll
        for (int j = 0; j < 8; ++j) {
#pragma unroll
            for (int r = 0; r < 4; ++r) {
                int m = m0 + wm + i * 16 + quad * 4 + r;
                int n = n0 + wn + j * 16 + l15;
                float val = (acc[i][j][r] + bias[n]) * scale;
                if (mode == 0) {
                    reinterpret_cast<float*>(out)[(size_t)m * 1024 + n] = val;
                } else {
                    int b_ = m >> 11, s = m & 2047, h = n >> 6, d = n & 63;
                    size_t off = (mode == 1)
                                     ? ((size_t)((b_ * 16 + h) * 2048 + s) * 64 + d)
                                     : ((size_t)((b_ * 16 + h) * 64 + d) * 2048 + s);
                    reinterpret_cast<unsigned short*>(out)[off] = (unsigned short)f2bf(val);
                }
            }
        }
    }
}

struct QkvArgs {
    const unsigned short* A[3];
    const unsigned short* W[3];
    const float* bias[3];
    float scale[3];
    unsigned short* out[3];
    int mode[3];
};
__global__ __launch_bounds__(512, 2) void gemm_qkv(QkvArgs ga) {
    int z = blockIdx.z;
    gemm_core<256, 256>(ga.A[z], ga.W[z], ga.bias[z], ga.scale[z], ga.out[z], ga.mode[z]);
}

__global__ __launch_bounds__(256, 2) void gemm_wo(const unsigned short* __restrict__ A,
                                                  const unsigned short* __restrict__ W,
                                                  const float* __restrict__ bias,
                                                  float* __restrict__ out) {
    gemm_core<256, 128>(A, W, bias, 1.0f, out, 0);
}

// ---- Flash v6: BQ=256, BKV=32, 512 threads (8 waves x 32 q), ping-pong ----
// Qh,Kh: [64][2048][64]; Vt: [64][64][2048]; Oa: [8192][1024] bf16.
// Q pre-scaled by 0.125*log2(e) -> exp2 directly.
__global__ __launch_bounds__(512, 4) void flash_attn(const unsigned short* __restrict__ Qh,
                                                     const unsigned short* __restrict__ Kh,
                                                     const unsigned short* __restrict__ Vt,
                                                     unsigned short* __restrict__ Oa) {
    constexpr int LD = 40;  // P row stride (elems); 80B = 5*16 aligned
    __shared__ unsigned short Ks[2][32 * 64];  // K tile [kv][d], swizzled chunks
    __shared__ unsigned short Vs[2][64 * 32];  // V^T tile [d][kv], swizzled
    __shared__ unsigned short Ps[8][32 * LD];  // wave-private 32q x 32kv
    const int tid = threadIdx.x;
    const int bh = blockIdx.y;
    const int q0 = blockIdx.x * 256;
    const unsigned short* Qb = Qh + (size_t)bh * 2048 * 64;
    const unsigned short* Kb = Kh + (size_t)bh * 2048 * 64;
    const unsigned short* Vb = Vt + (size_t)bh * 64 * 2048;
    const int wave = tid >> 6, lane = tid & 63;
    const int l15 = lane & 15, quad = lane >> 4;
    const int wq = wave * 32;
    unsigned short* Pw = Ps[wave];

    // staging assignment: threads 0..255 stage K (256 chunks), 256..511 stage V.
    const int stK = tid < 256;
    const int su = tid & 255;
    const int krow = su >> 3, kch = (su & 7) ^ (krow & 7);  // K: 32 rows x 8 chunks
    const int vrow = su >> 2, vch = (su & 3) ^ (vrow & 3);  // V: 64 rows x 4 chunks

#define STAGE_KV(KV0, PB)                                                        \
    {                                                                            \
        if (stK)                                                                 \
            gll16(&Kb[(size_t)((KV0) + krow) * 64 + kch * 8], &Ks[PB][su * 8]);  \
        else                                                                     \
            gll16(&Vb[(size_t)vrow * 2048 + (KV0) + vch * 8], &Vs[PB][su * 8]);  \
    }

    // Q fragments (B-operand of S^T = K·Q^T): loop-invariant registers.
    bf16x8 qreg[2][2];
#pragma unroll
    for (int i = 0; i < 2; ++i)
#pragma unroll
        for (int kk = 0; kk < 2; ++kk)
            qreg[i][kk] = *reinterpret_cast<const bf16x8*>(
                &Qb[(size_t)(q0 + wq + i * 16 + l15) * 64 + kk * 32 + quad * 8]);

    bf16x8 ones;
#pragma unroll
    for (int j = 0; j < 8; ++j) ones[j] = (short)0x3F80;  // bf16 1.0

    f32x4 o[2][4] = {};
    f32x4 lacc[2] = {};

    STAGE_KV(0, 0);
    __syncthreads();

    for (int it = 0; it < 64; ++it) {
        const int pb = it & 1;
        if (it < 63) STAGE_KV((it + 1) * 32, pb ^ 1);

        // S^T[kv=32][q=32/wave] = K·Q^T
        f32x4 sacc[2][2] = {};
#pragma unroll
        for (int kk = 0; kk < 2; ++kk) {
            bf16x8 ak[2];
#pragma unroll
            for (int j = 0; j < 2; ++j) {
                int row = j * 16 + l15;
                ak[j] = *reinterpret_cast<bf16x8*>(
                    &Ks[pb][row * 64 + (((kk * 4 + quad) ^ (row & 7)) * 8)]);
            }
#pragma unroll
            for (int i = 0; i < 2; ++i)
#pragma unroll
                for (int j = 0; j < 2; ++j)
                    sacc[i][j] = __builtin_amdgcn_mfma_f32_16x16x32_bf16(ak[j], qreg[i][kk], sacc[i][j], 0, 0, 0);
        }

        // p = exp2(s); pack pairs (+0x8000) -> wave-private P rows.
#pragma unroll
        for (int i = 0; i < 2; ++i) {
#pragma unroll
            for (int j = 0; j < 2; ++j) {
                float p0 = __builtin_amdgcn_exp2f(sacc[i][j][0]);
                float p1 = __builtin_amdgcn_exp2f(sacc[i][j][1]);
                float p2 = __builtin_amdgcn_exp2f(sacc[i][j][2]);
                float p3 = __builtin_amdgcn_exp2f(sacc[i][j][3]);
                union { float f; unsigned u; } a0{p0}, a1{p1}, a2{p2}, a3{p3};
                unsigned lo = __builtin_amdgcn_perm(a1.u + 0x8000u, a0.u + 0x8000u, 0x07060302u);
                unsigned hi = __builtin_amdgcn_perm(a3.u + 0x8000u, a2.u + 0x8000u, 0x07060302u);
                uint2 pk; pk.x = lo; pk.y = hi;
                *reinterpret_cast<uint2*>(&Pw[(i * 16 + l15) * LD + j * 16 + quad * 4]) = pk;
            }
        }

        // O += P·V ; l += P·ones  (single k-step: kv=32)
        bf16x8 ap[2];
#pragma unroll
        for (int i = 0; i < 2; ++i)
            ap[i] = *reinterpret_cast<bf16x8*>(&Pw[(i * 16 + l15) * LD + quad * 8]);
#pragma unroll
        for (int i = 0; i < 2; ++i)
            lacc[i] = __builtin_amdgcn_mfma_f32_16x16x32_bf16(ap[i], ones, lacc[i], 0, 0, 0);
#pragma unroll
        for (int n = 0; n < 4; ++n) {
            int row = n * 16 + l15;
            bf16x8 bv = *reinterpret_cast<bf16x8*>(
                &Vs[pb][row * 32 + ((quad ^ (row & 3)) * 8)]);
#pragma unroll
            for (int i = 0; i < 2; ++i)
                o[i][n] = __builtin_amdgcn_mfma_f32_16x16x32_bf16(ap[i], bv, o[i][n], 0, 0, 0);
        }
        __syncthreads();
    }
#undef STAGE_KV

    // epilogue: rinv from lacc (already in o's row layout), store bf16 token layout
    const int b_ = bh >> 4, h = bh & 15;
#pragma unroll
    for (int i = 0; i < 2; ++i) {
        f32x4 rv;
#pragma unroll
        for (int r = 0; r < 4; ++r) rv[r] = 1.0f / lacc[i][r];
#pragma unroll
        for (int n = 0; n < 4; ++n)
#pragma unroll
            for (int r = 0; r < 4; ++r) {
                int s = q0 + wq + i * 16 + quad * 4 + r;
                int d = n * 16 + l15;
                Oa[(size_t)(b_ * 2048 + s) * 1024 + h * 64 + d] =
                    (unsigned short)f2bf(o[i][n][r] * rv[r]);
            }
    }
}

extern "C" void kernel_launch(void* const* d_in, const int* in_sizes, int n_in,
                              void* d_out, int out_size, void* d_ws, size_t ws_size,
                              hipStream_t stream) {
    const float* q  = (const float*)d_in[0];
    const float* k  = (const float*)d_in[1];
    const float* v  = (const float*)d_in[2];
    const float* Wq = (const float*)d_in[3];
    const float* bq = (const float*)d_in[4];
    const float* Wk = (const float*)d_in[5];
    const float* bk = (const float*)d_in[6];
    const float* Wv = (const float*)d_in[7];
    const float* bv = (const float*)d_in[8];
    const float* Wo = (const float*)d_in[9];
    const float* bo = (const float*)d_in[10];

    const size_t E = (size_t)8192 * 1024;
    const size_t WE = (size_t)1024 * 1024;
    // aliasing (sequential dependency chain): r0=q_bf->Kh ; r1=k_bf->Vt ; r2=v_bf->Ao ; r3=Qh
    unsigned short* r0 = (unsigned short*)d_ws;
    unsigned short* r1 = r0 + E;
    unsigned short* r2 = r1 + E;
    unsigned short* r3 = r2 + E;
    unsigned short* wqb = r3 + E;
    unsigned short* wkb = wqb + WE;
    unsigned short* wvb = wkb + WE;
    unsigned short* wob = wvb + WE;

    CvtArgs ca;
    ca.s[0] = q; ca.d[0] = r0;
    ca.s[1] = k; ca.d[1] = r1;
    ca.s[2] = v; ca.d[2] = r2;
    ca.s[3] = q; ca.d[3] = r0;  // unused (grid.y = 3)
    ca.n4 = (int)(E / 4);
    cvt_bf16<<<dim3(1024, 3), 256, 0, stream>>>(ca);

    CvtArgs cw;
    cw.s[0] = Wq; cw.d[0] = wqb;
    cw.s[1] = Wk; cw.d[1] = wkb;
    cw.s[2] = Wv; cw.d[2] = wvb;
    cw.s[3] = Wo; cw.d[3] = wob;
    cw.n4 = (int)(WE / 4);
    cvt_bf16<<<dim3(256, 4), 256, 0, stream>>>(cw);

    const float QSCALE = 0.125f * 1.44269504088896340736f;  // fold log2(e) for exp2

    QkvArgs ga;
    ga.A[0] = r0; ga.W[0] = wqb; ga.bias[0] = bq; ga.scale[0] = QSCALE; ga.out[0] = r3; ga.mode[0] = 1;
    ga.A[1] = r1; ga.W[1] = wkb; ga.bias[1] = bk; ga.scale[1] = 1.0f;   ga.out[1] = r0; ga.mode[1] = 1;
    ga.A[2] = r2; ga.W[2] = wvb; ga.bias[2] = bv; ga.scale[2] = 1.0f;   ga.out[2] = r1; ga.mode[2] = 2;
    gemm_qkv<<<dim3(4, 32, 3), 512, 0, stream>>>(ga);

    flash_attn<<<dim3(8, 64), 512, 0, stream>>>(r3, r0, r1, r2);  // Ao = r2
    gemm_wo<<<dim3(8, 32), 256, 0, stream>>>(r2, wob, bo, (float*)d_out);
}